// Round 4
// baseline (381.426 us; speedup 1.0000x reference)
//
#include <hip/hip_runtime.h>

#define T_SEQ 256
#define PH  72
#define HSZ 1152
#define XRW 144          // x frag-tile row stride (halves): 72 dw -> spread banks
#define XSL 584          // per-t-slot stride (4*XRW + 8 pad) halves; 292 dw, %32=4

typedef float f32x4 __attribute__((ext_vector_type(4)));
typedef _Float16 f16x8 __attribute__((ext_vector_type(8)));

__device__ __forceinline__ float sigmoid_f(float x) {
    float e = __builtin_amdgcn_exp2f(-1.4426950408889634f * x);
    return __builtin_amdgcn_rcpf(1.0f + e);
}
__device__ __forceinline__ float tanh_f(float x) {
    float e = __builtin_amdgcn_exp2f(-2.8853900817779268f * x);
    return 2.0f * __builtin_amdgcn_rcpf(1.0f + e) - 1.0f;
}
__device__ __forceinline__ f16x8 load_frag16h(const float* wp, int n, int K, int k0) {
    const float* wf = wp + (size_t)n * K + k0;
    f16x8 h;
    #pragma unroll
    for (int j = 0; j < 8; ++j) h[j] = (_Float16)wf[j];
    return h;
}
__device__ __forceinline__ void load_frag16(const float* wp, int n, int K, int k0,
                                            f16x8& hi, f16x8& lo) {
    const float* wf = wp + (size_t)n * K + k0;
    #pragma unroll
    for (int j = 0; j < 8; ++j) {
        const float v = wf[j];
        const _Float16 h = (_Float16)v;
        hi[j] = h;
        lo[j] = (_Float16)(v - (float)h);
    }
}
__device__ __forceinline__ void gload16(const void* g, void* l) {
    __builtin_amdgcn_global_load_lds(
        (const __attribute__((address_space(1))) unsigned int*)g,
        (__attribute__((address_space(3))) unsigned int*)l, 16, 0, 0);
}

#define MFMA16(a, b, c) __builtin_amdgcn_mfma_f32_16x16x32_f16(a, b, c, 0, 0, 0)

// ================= fused rec v7: critical-chain shortened =================
// 256 blocks x 512 thr (8 waves). bb = blockIdx&63, sub = blockIdx>>6.
// Real rows: global row bb*16 + quad*4 + sub.
// Weight overlay (single union, no spill):
//   L1 (w<4): fA=wih1-hi (K=64), fB[0..1]=whh1-hi, fB[2..3]=whh1-lo
//   L0      : fA=whh0-hi, fAl=whh0-lo, fB[0..3]=wih0 f16 (K=128)
// Critical-chain changes vs v6:
//  - L0: x.wih0 for step t+1 precomputed into xacc[] BEFORE the barrier of
//    step t (xh is h-independent) -> post-barrier chain = 4 h-MFMAs only.
//  - L1: dual accumulators (4-deep + 2-deep chains, scalar add of elem 0).
//  - convert_chunk spread over 4 steps (2 ib each, tn%16=8..11) to smooth skew.
__global__ __launch_bounds__(512, 2) void rec_fused(
    const float* __restrict__ x,
    const float* __restrict__ wih0, const float* __restrict__ whh0,
    const float* __restrict__ bih0, const float* __restrict__ bhh0,
    const float* __restrict__ wih1, const float* __restrict__ whh1,
    const float* __restrict__ bih1, const float* __restrict__ bhh1,
    const float* __restrict__ wfc,  const float* __restrict__ bfc,
    float* __restrict__ out)
{
    __shared__ float    xs32[4 * 2048];          // 32,768 B staging strip
    __shared__ _Float16 xh[32 * XSL];            // 37,376 B x frags (f16)
    __shared__ _Float16 h0[2 * HSZ], h1[2 * HSZ];
    const int tid = threadIdx.x, lane = tid & 63, w = tid >> 6;
    const int l16 = lane & 15, quad = lane >> 4, k0 = quad * 8;
    const int wl = w & 3;
    const bool is1 = (w < 4);
    const int bb  = blockIdx.x & 63;
    const int sub = blockIdx.x >> 6;

    const float* xrow = x + (size_t)(bb * 16 + wl * 4 + sub) * 128 * 256;

    f16x8 fA[4][2], fAl[4][2], fB[4][4];
    float gb[4];
    #pragma unroll
    for (int g = 0; g < 4; ++g) {
        const int n = g * 64 + wl * 16 + l16;
        if (is1) {
            #pragma unroll
            for (int ks = 0; ks < 2; ++ks) {
                fA[g][ks] = load_frag16h(wih1, n, 64, ks * 32 + k0);
                load_frag16(whh1, n, 64, ks * 32 + k0, fB[g][ks], fB[g][2 + ks]);
            }
            gb[g] = bih1[n] + bhh1[n];
        } else {
            #pragma unroll
            for (int ks = 0; ks < 4; ++ks)
                fB[g][ks] = load_frag16h(wih0, n, 128, ks * 32 + k0);
            #pragma unroll
            for (int ks = 0; ks < 2; ++ks)
                load_frag16(whh0, n, 64, ks * 32 + k0, fA[g][ks], fAl[g][ks]);
            gb[g] = bih0[n] + bhh0[n];
        }
    }
    for (int i = tid; i < 2 * HSZ; i += 512) { h0[i] = (_Float16)0.f; h1[i] = (_Float16)0.f; }
    float c = 0.f;       // lane's cell state (c1 for L1, c0 for L0)
    f32x4 xacc[4];       // L0 only: precomputed bias + x.wih0 for the NEXT step

    // strip -> f16 frag-layout conversion, rows ib0..ib0+nib-1
    auto convert_rows = [&](int cc, int ib0, int nib) {
        const int sb = (cc & 1) * 16;
        const int tq = lane & 3;
        for (int ib = ib0; ib < ib0 + nib; ++ib) {
            const float4 v = *(const float4*)&xs32[wl * 2048 + ib * 256 + lane * 4];
            const int d = ib * 16 + (lane >> 2);
            const float vv[4] = {v.x, v.y, v.z, v.w};
            #pragma unroll
            for (int j = 0; j < 4; ++j)
                xh[(sb + tq * 4 + j) * XSL + wl * XRW + d] = (_Float16)vv[j];
        }
    };
    auto issue_chunk = [&](int cc) {
        #pragma unroll
        for (int ib = 0; ib < 8; ++ib)
            gload16(xrow + (size_t)(ib * 16 + (lane >> 2)) * 256 + cc * 16 + (lane & 3) * 4,
                    (char*)xs32 + wl * 8192 + ib * 1024);
    };
    // precompute xacc for time-slot `slot` (bias-init + 4 x-MFMAs; off-critical)
    auto precompute_x = [&](int slot) {
        f16x8 ax[4];
        #pragma unroll
        for (int ks = 0; ks < 4; ++ks)
            ax[ks] = *(const f16x8*)&xh[slot * XSL + (l16 >> 2) * XRW + ks * 32 + k0];
        #pragma unroll
        for (int g = 0; g < 4; ++g) xacc[g] = (f32x4){gb[g], 0.f, 0.f, 0.f};
        #pragma unroll
        for (int g = 0; g < 4; ++g)
            #pragma unroll
            for (int ks = 0; ks < 4; ++ks)
                xacc[g] = MFMA16(ax[ks], fB[g][ks], xacc[g]);
    };

    if (!is1) issue_chunk(0);
    __syncthreads();                 // chunk0 drained into strip; h zeroed
    if (!is1) { convert_rows(0, 0, 8); issue_chunk(1); }
    __syncthreads();                 // xh chunk0 visible; chunk1 drained

    if (!is1) {      // prologue: layer0 t=0 (h=0): gates = x.W + b
        precompute_x(0);
        const float gi = sigmoid_f(xacc[0][0]);
        const float gg = tanh_f(xacc[2][0]);
        const float go = sigmoid_f(xacc[3][0]);
        c = gi * gg;
        h0[(quad * 4) * PH + wl * 16 + l16] = (_Float16)(go * tanh_f(c));
        precompute_x(1);             // xacc ready for tn=1
    }
    __syncthreads();

    for (int t = 0; t < 255; ++t) {
        const int s0 = t & 1, s1 = s0 ^ 1;
        const int tn = t + 1;
        if (is1) {
            f16x8 ah[2], bh[2];
            #pragma unroll
            for (int ks = 0; ks < 2; ++ks) {
                ah[ks] = *(const f16x8*)&h0[s0 * HSZ + l16 * PH + ks * 32 + k0];
                bh[ks] = *(const f16x8*)&h1[s1 * HSZ + l16 * PH + ks * 32 + k0];
            }
            f32x4 accA[4], accB[4];
            #pragma unroll
            for (int g = 0; g < 4; ++g) {
                accA[g] = (f32x4){gb[g], 0.f, 0.f, 0.f};
                accB[g] = (f32x4){0.f, 0.f, 0.f, 0.f};
            }
            #pragma unroll
            for (int g = 0; g < 4; ++g)
                #pragma unroll
                for (int ks = 0; ks < 2; ++ks) {
                    accA[g] = MFMA16(ah[ks], fA[g][ks], accA[g]);
                    accA[g] = MFMA16(bh[ks], fB[g][ks], accA[g]);
                    accB[g] = MFMA16(bh[ks], fB[g][2 + ks], accB[g]);
                }
            const float gi = sigmoid_f(accA[0][0] + accB[0][0]);
            const float gf = sigmoid_f(accA[1][0] + accB[1][0]);
            const float gg = tanh_f(accA[2][0] + accB[2][0]);
            const float go = sigmoid_f(accA[3][0] + accB[3][0]);
            c = gf * c + gi * gg;
            h1[s0 * HSZ + (quad * 4) * PH + wl * 16 + l16] =
                (_Float16)(go * tanh_f(c));
        } else {
            if ((tn & 15) == 0 && tn < 240)       // issue next chunk (async DMA)
                issue_chunk((tn >> 4) + 1);
            f16x8 ah[2];
            #pragma unroll
            for (int ks = 0; ks < 2; ++ks)
                ah[ks] = *(const f16x8*)&h0[s0 * HSZ + l16 * PH + ks * 32 + k0];
            f32x4 acc[4];
            #pragma unroll
            for (int g = 0; g < 4; ++g) acc[g] = xacc[g];
            #pragma unroll
            for (int g = 0; g < 4; ++g)
                #pragma unroll
                for (int ks = 0; ks < 2; ++ks) {
                    acc[g] = MFMA16(ah[ks], fA[g][ks], acc[g]);
                    acc[g] = MFMA16(ah[ks], fAl[g][ks], acc[g]);
                }
            const float gi = sigmoid_f(acc[0][0]);
            const float gf = sigmoid_f(acc[1][0]);
            const float gg = tanh_f(acc[2][0]);
            const float go = sigmoid_f(acc[3][0]);
            c = gf * c + gi * gg;
            h0[s1 * HSZ + (quad * 4) * PH + wl * 16 + l16] =
                (_Float16)(go * tanh_f(c));
            // ---- pre-barrier (h-independent) work ----
            const int m16 = tn & 15;
            if (m16 >= 8 && m16 < 12 && tn < 248)   // spread strip->frag convert
                convert_rows((tn >> 4) + 1, (m16 - 8) * 2, 2);
            if (tn < 255) {                         // xacc for step tn+1
                const int tn2 = tn + 1;
                precompute_x(((tn2 >> 4) & 1) * 16 + (tn2 & 15));
            }
        }
        __syncthreads();
    }

    if (is1) {   // epilogue: layer1[255] (h0 slot1, h1 slot0 -> h1 slot1)
        f16x8 ah[2], bh[2];
        #pragma unroll
        for (int ks = 0; ks < 2; ++ks) {
            ah[ks] = *(const f16x8*)&h0[HSZ + l16 * PH + ks * 32 + k0];
            bh[ks] = *(const f16x8*)&h1[l16 * PH + ks * 32 + k0];
        }
        f32x4 accA[4], accB[4];
        #pragma unroll
        for (int g = 0; g < 4; ++g) {
            accA[g] = (f32x4){gb[g], 0.f, 0.f, 0.f};
            accB[g] = (f32x4){0.f, 0.f, 0.f, 0.f};
        }
        #pragma unroll
        for (int g = 0; g < 4; ++g)
            #pragma unroll
            for (int ks = 0; ks < 2; ++ks) {
                accA[g] = MFMA16(ah[ks], fA[g][ks], accA[g]);
                accA[g] = MFMA16(bh[ks], fB[g][ks], accA[g]);
                accB[g] = MFMA16(bh[ks], fB[g][2 + ks], accB[g]);
            }
        const float gi = sigmoid_f(accA[0][0] + accB[0][0]);
        const float gf = sigmoid_f(accA[1][0] + accB[1][0]);
        const float gg = tanh_f(accA[2][0] + accB[2][0]);
        const float go = sigmoid_f(accA[3][0] + accB[3][0]);
        c = gf * c + gi * gg;
        h1[HSZ + (quad * 4) * PH + wl * 16 + l16] = (_Float16)(go * tanh_f(c));
    }
    __syncthreads();

    // head: row m = sel*4 (slot 1); out row = bb*16 + sel*4 + sub
    const int n   = tid & 127;
    const int sel = tid >> 7;
    float s = 0.f;
    for (int k = 0; k < 64; ++k)
        s += (float)h1[HSZ + (sel * 4) * PH + k] * wfc[n * 64 + k];
    out[(size_t)(bb * 16 + sel * 4 + sub) * 128 + n] = s + bfc[n];
}

extern "C" void kernel_launch(void* const* d_in, const int* in_sizes, int n_in,
                              void* d_out, int out_size, void* d_ws, size_t ws_size,
                              hipStream_t stream) {
    const float* x     = (const float*)d_in[0];
    const float* wih0  = (const float*)d_in[1];
    const float* whh0  = (const float*)d_in[2];
    const float* bih0  = (const float*)d_in[3];
    const float* bhh0  = (const float*)d_in[4];
    const float* wih1  = (const float*)d_in[5];
    const float* whh1  = (const float*)d_in[6];
    const float* bih1  = (const float*)d_in[7];
    const float* bhh1  = (const float*)d_in[8];
    const float* wfc   = (const float*)d_in[9];
    const float* bfc   = (const float*)d_in[10];
    float* out = (float*)d_out;

    rec_fused<<<256, 512, 0, stream>>>(x, wih0, whh0, bih0, bhh0,
                                       wih1, whh1, bih1, bhh1, wfc, bfc, out);
}

// Round 5
// 365.818 us; speedup vs baseline: 1.0427x; 1.0427x over previous
//
#include <hip/hip_runtime.h>

#define PH  72
#define HSZ 1152
#define XRW 144          // x frag-tile row stride (halves)
#define XSL 584          // per-t-slot stride (4*XRW + 8 pad) halves

typedef float f32x4 __attribute__((ext_vector_type(4)));
typedef _Float16 f16x8 __attribute__((ext_vector_type(8)));

__device__ __forceinline__ float sigmoid_f(float x) {
    float e = __builtin_amdgcn_exp2f(-1.4426950408889634f * x);
    return __builtin_amdgcn_rcpf(1.0f + e);
}
__device__ __forceinline__ float tanh_f(float x) {
    float e = __builtin_amdgcn_exp2f(-2.8853900817779268f * x);
    return 2.0f * __builtin_amdgcn_rcpf(1.0f + e) - 1.0f;
}
__device__ __forceinline__ f16x8 load_frag16h(const float* wp, int n, int K, int k0) {
    const float* wf = wp + (size_t)n * K + k0;
    f16x8 h;
    #pragma unroll
    for (int j = 0; j < 8; ++j) h[j] = (_Float16)wf[j];
    return h;
}
__device__ __forceinline__ void load_frag16(const float* wp, int n, int K, int k0,
                                            f16x8& hi, f16x8& lo) {
    const float* wf = wp + (size_t)n * K + k0;
    #pragma unroll
    for (int j = 0; j < 8; ++j) {
        const float v = wf[j];
        const _Float16 h = (_Float16)v;
        hi[j] = h;
        lo[j] = (_Float16)(v - (float)h);
    }
}
__device__ __forceinline__ void gload16(const void* g, void* l) {
    __builtin_amdgcn_global_load_lds(
        (const __attribute__((address_space(1))) unsigned int*)g,
        (__attribute__((address_space(3))) unsigned int*)l, 16, 0, 0);
}

#define MFMA16(a, b, c) __builtin_amdgcn_mfma_f32_16x16x32_f16(a, b, c, 0, 0, 0)

// ======= fused rec v8: producer/consumer wave specialization =======
// 256 blocks x 768 thr (12 waves: 4 L1, 4 L0, 4 proj; one of each per SIMD).
// bb = blockIdx&63, sub = blockIdx>>6. Real rows: bb*16 + quad*4 + sub.
// proj waves (w>=8): own ALL x work — strip staging (gload_lds), strip->frag
//   convert, frag read, and xp[t+2] = b0 + x.wih0 MFMAs -> f32 LDS ring (4 slots).
// L0 waves (w 4..7): ds_read_b128 xp[tn] + 16 h.whh0 MFMAs (dual-acc, 2-deep)
//   -> gates -> h0[s1]. Post-barrier chain: read + 2 MFMA + act + write.
// L1 waves (w<4): as v7 (dual-acc, wih1-hi + whh1 hi/lo, 24 MFMA).
// Weight overlay: fA[4][2] + fB[4][4] = 96 VGPR static union:
//   L1: fA=wih1-hi, fB[0..1]=whh1-hi, fB[2..3]=whh1-lo
//   L0: fA=whh0-hi, fB[2..3]=whh0-lo
//   proj: fB[0..3]=wih0 (f16, K=128)
__global__ __launch_bounds__(768, 3) void rec_fused(
    const float* __restrict__ x,
    const float* __restrict__ wih0, const float* __restrict__ whh0,
    const float* __restrict__ bih0, const float* __restrict__ bhh0,
    const float* __restrict__ wih1, const float* __restrict__ whh1,
    const float* __restrict__ bih1, const float* __restrict__ bhh1,
    const float* __restrict__ wfc,  const float* __restrict__ bfc,
    float* __restrict__ out)
{
    __shared__ float    xs32[4 * 2048];          // 32 KB staging strip
    __shared__ _Float16 xh[32 * XSL];            // 37,376 B x frags (f16)
    __shared__ float    xpl[4 * 1024];           // 16 KB xp ring (4 t-slots)
    __shared__ _Float16 h0[2 * HSZ], h1[2 * HSZ];
    const int tid = threadIdx.x, lane = tid & 63, w = tid >> 6;
    const int l16 = lane & 15, quad = lane >> 4, k0 = quad * 8;
    const int wl = w & 3;
    const int role = w >> 2;                     // 0=L1, 1=L0, 2=proj
    const bool is1 = (role == 0), is0 = (role == 1), isP = (role == 2);
    const int bb  = blockIdx.x & 63;
    const int sub = blockIdx.x >> 6;

    const float* xrow = x + (size_t)(bb * 16 + wl * 4 + sub) * 128 * 256;

    f16x8 fA[4][2], fB[4][4];
    float gb[4] = {0.f, 0.f, 0.f, 0.f};
    #pragma unroll
    for (int g = 0; g < 4; ++g) {
        const int n = g * 64 + wl * 16 + l16;
        if (is1) {
            #pragma unroll
            for (int ks = 0; ks < 2; ++ks) {
                fA[g][ks] = load_frag16h(wih1, n, 64, ks * 32 + k0);
                load_frag16(whh1, n, 64, ks * 32 + k0, fB[g][ks], fB[g][2 + ks]);
            }
            gb[g] = bih1[n] + bhh1[n];
        } else if (is0) {
            #pragma unroll
            for (int ks = 0; ks < 2; ++ks)
                load_frag16(whh0, n, 64, ks * 32 + k0, fA[g][ks], fB[g][2 + ks]);
        } else {
            #pragma unroll
            for (int ks = 0; ks < 4; ++ks)
                fB[g][ks] = load_frag16h(wih0, n, 128, ks * 32 + k0);
            gb[g] = bih0[n] + bhh0[n];
        }
    }
    for (int i = tid; i < 2 * HSZ; i += 768) { h0[i] = (_Float16)0.f; h1[i] = (_Float16)0.f; }
    float c = 0.f;       // lane's cell state (c1 for L1, c0 for L0)

    // ---- proj-wave helpers ----
    auto convert_rows = [&](int cc, int ib0, int nib) {
        const int sb = (cc & 1) * 16;
        const int tq = lane & 3;
        for (int ib = ib0; ib < ib0 + nib; ++ib) {
            const float4 v = *(const float4*)&xs32[wl * 2048 + ib * 256 + lane * 4];
            const int d = ib * 16 + (lane >> 2);
            const float vv[4] = {v.x, v.y, v.z, v.w};
            #pragma unroll
            for (int j = 0; j < 4; ++j)
                xh[(sb + tq * 4 + j) * XSL + wl * XRW + d] = (_Float16)vv[j];
        }
    };
    auto issue_chunk = [&](int cc) {
        #pragma unroll
        for (int ib = 0; ib < 8; ++ib)
            gload16(xrow + (size_t)(ib * 16 + (lane >> 2)) * 256 + cc * 16 + (lane & 3) * 4,
                    (char*)xs32 + wl * 8192 + ib * 1024);
    };
    // produce xp[tp] = b0 + x.wih0 into ring slot tp&3 (f32x4 per lane, g=0..3)
    auto compute_xp = [&](int tp) {
        const int fs = ((tp >> 4) & 1) * 16 + (tp & 15);
        f16x8 ax[4];
        #pragma unroll
        for (int ks = 0; ks < 4; ++ks)
            ax[ks] = *(const f16x8*)&xh[fs * XSL + (l16 >> 2) * XRW + ks * 32 + k0];
        f32x4 pa[4];
        #pragma unroll
        for (int g = 0; g < 4; ++g) pa[g] = (f32x4){gb[g], 0.f, 0.f, 0.f};
        #pragma unroll
        for (int g = 0; g < 4; ++g)
            #pragma unroll
            for (int ks = 0; ks < 4; ++ks)
                pa[g] = MFMA16(ax[ks], fB[g][ks], pa[g]);
        f32x4 o;
        o[0] = pa[0][0]; o[1] = pa[1][0]; o[2] = pa[2][0]; o[3] = pa[3][0];
        *(f32x4*)&xpl[(((tp & 3) * 4 + wl) * 64 + lane) * 4] = o;
    };

    if (isP) issue_chunk(0);
    __syncthreads();                 // chunk0 drained; h zeroed
    if (isP) { convert_rows(0, 0, 8); issue_chunk(1); }
    __syncthreads();                 // xh chunk0 visible; chunk1 drained
    if (isP) { compute_xp(0); compute_xp(1); }
    __syncthreads();                 // xp[0], xp[1] visible
    if (is0) {                       // prologue: layer0 t=0 (h=0)
        const f32x4 xp4 = *(const f32x4*)&xpl[(wl * 64 + lane) * 4];
        const float gi = sigmoid_f(xp4[0]);
        const float gg = tanh_f(xp4[2]);
        const float go = sigmoid_f(xp4[3]);
        c = gi * gg;
        h0[(quad * 4) * PH + wl * 16 + l16] = (_Float16)(go * tanh_f(c));
    }
    __syncthreads();

    for (int t = 0; t < 255; ++t) {
        const int s0 = t & 1, s1 = s0 ^ 1;
        const int tn = t + 1;
        if (is1) {
            f16x8 ah[2], bh[2];
            #pragma unroll
            for (int ks = 0; ks < 2; ++ks) {
                ah[ks] = *(const f16x8*)&h0[s0 * HSZ + l16 * PH + ks * 32 + k0];
                bh[ks] = *(const f16x8*)&h1[s1 * HSZ + l16 * PH + ks * 32 + k0];
            }
            f32x4 accA[4], accB[4];
            #pragma unroll
            for (int g = 0; g < 4; ++g) {
                accA[g] = (f32x4){gb[g], 0.f, 0.f, 0.f};
                accB[g] = (f32x4){0.f, 0.f, 0.f, 0.f};
            }
            #pragma unroll
            for (int g = 0; g < 4; ++g)
                #pragma unroll
                for (int ks = 0; ks < 2; ++ks) {
                    accA[g] = MFMA16(ah[ks], fA[g][ks], accA[g]);
                    accA[g] = MFMA16(bh[ks], fB[g][ks], accA[g]);
                    accB[g] = MFMA16(bh[ks], fB[g][2 + ks], accB[g]);
                }
            const float gi = sigmoid_f(accA[0][0] + accB[0][0]);
            const float gf = sigmoid_f(accA[1][0] + accB[1][0]);
            const float gg = tanh_f(accA[2][0] + accB[2][0]);
            const float go = sigmoid_f(accA[3][0] + accB[3][0]);
            c = gf * c + gi * gg;
            h1[s0 * HSZ + (quad * 4) * PH + wl * 16 + l16] =
                (_Float16)(go * tanh_f(c));
        } else if (is0) {
            const f32x4 xp4 =
                *(const f32x4*)&xpl[(((tn & 3) * 4 + wl) * 64 + lane) * 4];
            f16x8 ah[2];
            #pragma unroll
            for (int ks = 0; ks < 2; ++ks)
                ah[ks] = *(const f16x8*)&h0[s0 * HSZ + l16 * PH + ks * 32 + k0];
            f32x4 accA[4], accB[4];
            #pragma unroll
            for (int g = 0; g < 4; ++g) {
                accA[g] = (f32x4){xp4[g], 0.f, 0.f, 0.f};
                accB[g] = (f32x4){0.f, 0.f, 0.f, 0.f};
            }
            #pragma unroll
            for (int g = 0; g < 4; ++g)
                #pragma unroll
                for (int ks = 0; ks < 2; ++ks) {
                    accA[g] = MFMA16(ah[ks], fA[g][ks], accA[g]);
                    accB[g] = MFMA16(ah[ks], fB[g][2 + ks], accB[g]);
                }
            const float gi = sigmoid_f(accA[0][0] + accB[0][0]);
            const float gf = sigmoid_f(accA[1][0] + accB[1][0]);
            const float gg = tanh_f(accA[2][0] + accB[2][0]);
            const float go = sigmoid_f(accA[3][0] + accB[3][0]);
            c = gf * c + gi * gg;
            h0[s1 * HSZ + (quad * 4) * PH + wl * 16 + l16] =
                (_Float16)(go * tanh_f(c));
        } else {
            if ((tn & 15) == 0 && tn < 240)         // issue next chunk (DMA)
                issue_chunk((tn >> 4) + 1);
            const int m16 = tn & 15;
            if (m16 >= 8 && m16 < 12 && tn < 248)   // spread strip->frag convert
                convert_rows((tn >> 4) + 1, (m16 - 8) * 2, 2);
            const int tp = t + 2;                   // produce xp 2 steps ahead
            if (tp <= 255) compute_xp(tp);
        }
        __syncthreads();
    }

    if (is1) {   // epilogue: layer1[255] (h0 slot1, h1 slot0 -> h1 slot1)
        f16x8 ah[2], bh[2];
        #pragma unroll
        for (int ks = 0; ks < 2; ++ks) {
            ah[ks] = *(const f16x8*)&h0[HSZ + l16 * PH + ks * 32 + k0];
            bh[ks] = *(const f16x8*)&h1[l16 * PH + ks * 32 + k0];
        }
        f32x4 accA[4], accB[4];
        #pragma unroll
        for (int g = 0; g < 4; ++g) {
            accA[g] = (f32x4){gb[g], 0.f, 0.f, 0.f};
            accB[g] = (f32x4){0.f, 0.f, 0.f, 0.f};
        }
        #pragma unroll
        for (int g = 0; g < 4; ++g)
            #pragma unroll
            for (int ks = 0; ks < 2; ++ks) {
                accA[g] = MFMA16(ah[ks], fA[g][ks], accA[g]);
                accA[g] = MFMA16(bh[ks], fB[g][ks], accA[g]);
                accB[g] = MFMA16(bh[ks], fB[g][2 + ks], accB[g]);
            }
        const float gi = sigmoid_f(accA[0][0] + accB[0][0]);
        const float gf = sigmoid_f(accA[1][0] + accB[1][0]);
        const float gg = tanh_f(accA[2][0] + accB[2][0]);
        const float go = sigmoid_f(accA[3][0] + accB[3][0]);
        c = gf * c + gi * gg;
        h1[HSZ + (quad * 4) * PH + wl * 16 + l16] = (_Float16)(go * tanh_f(c));
    }
    __syncthreads();

    // head: row m = sel*4 (slot 1); out row = bb*16 + sel*4 + sub
    if (tid < 512) {
        const int n   = tid & 127;
        const int sel = tid >> 7;
        float s = 0.f;
        for (int k = 0; k < 64; ++k)
            s += (float)h1[HSZ + (sel * 4) * PH + k] * wfc[n * 64 + k];
        out[(size_t)(bb * 16 + sel * 4 + sub) * 128 + n] = s + bfc[n];
    }
}

extern "C" void kernel_launch(void* const* d_in, const int* in_sizes, int n_in,
                              void* d_out, int out_size, void* d_ws, size_t ws_size,
                              hipStream_t stream) {
    const float* x     = (const float*)d_in[0];
    const float* wih0  = (const float*)d_in[1];
    const float* whh0  = (const float*)d_in[2];
    const float* bih0  = (const float*)d_in[3];
    const float* bhh0  = (const float*)d_in[4];
    const float* wih1  = (const float*)d_in[5];
    const float* whh1  = (const float*)d_in[6];
    const float* bih1  = (const float*)d_in[7];
    const float* bhh1  = (const float*)d_in[8];
    const float* wfc   = (const float*)d_in[9];
    const float* bfc   = (const float*)d_in[10];
    float* out = (float*)d_out;

    rec_fused<<<256, 768, 0, stream>>>(x, wih0, whh0, bih0, bhh0,
                                       wih1, whh1, bih1, bhh1, wfc, bfc, out);
}